// Round 1
// 116.582 us; speedup vs baseline: 1.0017x; 1.0017x over previous
//
#include <hip/hip_runtime.h>

// Problem constants (from reference):
//   BATCH=256, SEQ=512, VOCAB=100000, DIM=64, N_TABLES=3
//   inputs:    (256,512)  fp32 (integer-valued)
//   tables:    (3,100000,64) fp32
//   table_ids: (512,) int32, pattern [0,1,2,-1]
//   out:       (256,512,64) fp32
// out[b,s,:] = tables[table_ids[s], int(inputs[b,s]), :]  if table_ids[s]>=0
//            = inputs[b,s] broadcast over DIM             otherwise
//
// Structure: 8 threads per row, each thread moves two float4 (32 B).
//  - halves wave count vs 16-thr/row version, 2 independent loads per
//    thread for memory-level parallelism
//  - output is a pure stream (written once, never read): nontemporal
//    stores keep it from evicting gather-table lines out of L2
//  - table loads stay cached (L2/L3) — the 76.8 MB table is L3-resident

#define SEQ   512
#define VOCAB 100000
#define DIM   64

typedef float f4 __attribute__((ext_vector_type(4)));

__global__ __launch_bounds__(256) void
TransformerWord2VecEncoder_37804302139707_kernel(
    const float* __restrict__ inputs,     // [BATCH*SEQ]
    const float* __restrict__ tables,     // [3*VOCAB*DIM]
    const int*   __restrict__ table_ids,  // [SEQ]
    float*       __restrict__ out)        // [BATCH*SEQ*DIM]
{
    const int t    = blockIdx.x * 256 + threadIdx.x;
    const int r    = t >> 3;        // row index = b*SEQ + s
    const int lane = t & 7;         // which pair of float4 slots

    const int   s   = r & (SEQ - 1);
    const float val = inputs[r];
    const int   tid = table_ids[s];

    f4 res0, res1;
    if (tid >= 0) {
        const int idx = (int)val;   // integer-valued fp32 index
        const f4* src =
            (const f4*)(tables + ((size_t)tid * VOCAB + (size_t)idx) * DIM);
        res0 = src[lane];           // bytes [lane*16,      lane*16+16)
        res1 = src[lane + 8];       // bytes [128+lane*16, 128+lane*16+16)
    } else {
        res0 = (f4){val, val, val, val};
        res1 = res0;
    }

    f4* dst = (f4*)out + (size_t)r * (DIM / 4);
    __builtin_nontemporal_store(res0, dst + lane);
    __builtin_nontemporal_store(res1, dst + lane + 8);
}

extern "C" void kernel_launch(void* const* d_in, const int* in_sizes, int n_in,
                              void* d_out, int out_size, void* d_ws, size_t ws_size,
                              hipStream_t stream) {
    const float* inputs    = (const float*)d_in[0];  // (256,512) fp32
    const float* tables    = (const float*)d_in[1];  // (3,100000,64) fp32
    const int*   table_ids = (const int*)d_in[2];    // (512,) int32
    float*       out       = (float*)d_out;          // (256,512,64) fp32

    // total threads = BATCH*SEQ*8 = 1,048,576 -> 4096 blocks of 256
    const int n_rows = out_size / DIM;               // 131072
    const int blocks = (n_rows * 8) / 256;           // 4096
    TransformerWord2VecEncoder_37804302139707_kernel<<<blocks, 256, 0, stream>>>(
        inputs, tables, table_ids, out);
}